// Round 1
// baseline (107.094 us; speedup 1.0000x reference)
//
#include <hip/hip_runtime.h>
#include <hip/hip_bf16.h>

typedef __bf16 bf16x8 __attribute__((ext_vector_type(8)));
typedef float  f32x4  __attribute__((ext_vector_type(4)));

namespace {
constexpr int kB = 16;
constexpr int kT = 2048;
constexpr int kD = 128;
constexpr int RB = 128;   // rows per block (4 waves x 32 rows)
constexpr int CT = 64;    // columns per LDS tile
constexpr float TH_SIM  = 0.9f;
constexpr float TH_DIFF = 0.1f;
constexpr float BIGF    = 1e9f;
}

// ---------------------------------------------------------------- normalize
// One wave per row: 64 lanes x float2 = 128 elems; shfl-reduce sumsq;
// write normalized bf16. (sim = dot/max(w_i*w_j,EPS) == dot of unit vectors
// for this data regime: w ~ sqrt(128) >> EPS.)
__global__ __launch_bounds__(256) void nrm_kernel(const float* __restrict__ emb,
                                                  __hip_bfloat16* __restrict__ out) {
    const int wave = threadIdx.x >> 6;
    const int lane = threadIdx.x & 63;
    const size_t row = (size_t)blockIdx.x * 4 + wave;
    const float2 v = *reinterpret_cast<const float2*>(emb + row * kD + lane * 2);
    float ss = v.x * v.x + v.y * v.y;
    #pragma unroll
    for (int m = 1; m < 64; m <<= 1) ss += __shfl_xor(ss, m);
    const float inv = ss > 0.f ? rsqrtf(ss) : 0.f;
    __hip_bfloat162 o;
    o.x = __float2bfloat16(v.x * inv);
    o.y = __float2bfloat16(v.y * inv);
    *reinterpret_cast<__hip_bfloat162*>(out + row * kD + lane * 2) = o;
}

// ---------------------------------------------------------------- main
// Streaming Gram: per block = one 128-row stripe of one batch.
// Each wave owns 32 rows; loop 64-col tiles over all 2048 cols.
// Running per-row stats: min over same-label cols, max over other-label cols.
__global__ __launch_bounds__(256) void crloss_main(const __hip_bfloat16* __restrict__ nrm,
                                                   const int* __restrict__ label,
                                                   float* __restrict__ partials) {
    __shared__ __align__(16) short lds[CT * kD];   // 16 KiB, XOR-swizzled
    const int bid  = blockIdx.x;
    const int b    = bid >> 4;
    const int rb   = bid & 15;
    const int tid  = threadIdx.x;
    const int wave = tid >> 6;
    const int lane = tid & 63;
    const int lo   = lane & 15;
    const int hi   = lane >> 4;

    const short* nb = reinterpret_cast<const short*>(nrm) + (size_t)b * kT * kD;
    const int*   lb = label + b * kT;
    const int wave_row0 = rb * RB + wave * 32;

    // Hoist A fragments (rows fixed for whole kernel).
    // mfma_f32_16x16x32_bf16 A-layout: lane holds row (lane&15), k = (lane>>4)*8 + e
    bf16x8 afrag[2][4];
    #pragma unroll
    for (int rg = 0; rg < 2; ++rg)
        #pragma unroll
        for (int kk = 0; kk < 4; ++kk)
            afrag[rg][kk] = *reinterpret_cast<const bf16x8*>(
                nb + (size_t)(wave_row0 + rg * 16 + lo) * kD + kk * 32 + hi * 8);

    // Row labels for the rows this lane's accumulator covers:
    // D-layout: col = lane&15, row = (lane>>4)*4 + reg  => rows depend on hi only.
    bool frow[2][4];
    #pragma unroll
    for (int rg = 0; rg < 2; ++rg)
        #pragma unroll
        for (int r = 0; r < 4; ++r)
            frow[rg][r] = (lb[wave_row0 + rg * 16 + hi * 4 + r] == 0);

    float minS[2][4], maxO[2][4];
    #pragma unroll
    for (int rg = 0; rg < 2; ++rg)
        #pragma unroll
        for (int r = 0; r < 4; ++r) { minS[rg][r] = BIGF; maxO[rg][r] = -BIGF; }

    for (int ct = 0; ct < kT / CT; ++ct) {
        __syncthreads();   // protect lds vs previous iteration's readers
        // stage 64x128 bf16 col tile; swizzle byte offset by ((col&7)<<4)
        #pragma unroll
        for (int p = 0; p < 4; ++p) {
            const int c    = p * 256 + tid;
            const int col  = c >> 4;          // 16 chunks of 8 shorts per col
            const int offs = (c & 15) * 8;    // short offset within row
            const bf16x8 v = *reinterpret_cast<const bf16x8*>(
                nb + (size_t)(ct * CT + col) * kD + offs);
            *reinterpret_cast<bf16x8*>(&lds[col * kD + (offs ^ ((col & 7) << 3))]) = v;
        }
        __syncthreads();

        #pragma unroll
        for (int g = 0; g < 4; ++g) {
            const bool fcol = (lb[ct * CT + g * 16 + lo] == 0);
            bf16x8 bfrag[4];
            #pragma unroll
            for (int kk = 0; kk < 4; ++kk) {
                const int col  = g * 16 + lo;
                const int offs = kk * 32 + hi * 8;
                bfrag[kk] = *reinterpret_cast<const bf16x8*>(
                    &lds[col * kD + (offs ^ ((col & 7) << 3))]);
            }
            #pragma unroll
            for (int rg = 0; rg < 2; ++rg) {
                f32x4 acc = {0.f, 0.f, 0.f, 0.f};
                #pragma unroll
                for (int kk = 0; kk < 4; ++kk)
                    acc = __builtin_amdgcn_mfma_f32_16x16x32_bf16(
                        afrag[rg][kk], bfrag[kk], acc, 0, 0, 0);
                #pragma unroll
                for (int r = 0; r < 4; ++r) {
                    const float v = acc[r];
                    const bool other = (fcol != frow[rg][r]);
                    minS[rg][r] = fminf(minS[rg][r], other ? BIGF : v);
                    maxO[rg][r] = fmaxf(maxO[rg][r], other ? v : -BIGF);
                }
            }
        }
    }

    // combine the 16 lanes (same hi => same rows, different cols)
    #pragma unroll
    for (int m = 1; m <= 8; m <<= 1) {
        #pragma unroll
        for (int rg = 0; rg < 2; ++rg)
            #pragma unroll
            for (int r = 0; r < 4; ++r) {
                minS[rg][r] = fminf(minS[rg][r], __shfl_xor(minS[rg][r], m));
                maxO[rg][r] = fmaxf(maxO[rg][r], __shfl_xor(maxO[rg][r], m));
            }
    }

    // per-row loss contributions (one lane per 16-lane group contributes)
    float s[4] = {0.f, 0.f, 0.f, 0.f};   // f2f, r2r, f2r, r2f sums
    if (lo == 0) {
        #pragma unroll
        for (int rg = 0; rg < 2; ++rg)
            #pragma unroll
            for (int r = 0; r < 4; ++r) {
                if (frow[rg][r]) {
                    s[0] += fmaxf(TH_SIM - minS[rg][r], 0.f);
                    s[2] += fmaxf(maxO[rg][r] - TH_DIFF, 0.f);
                } else {
                    s[1] += fmaxf(TH_SIM - minS[rg][r], 0.f);
                    s[3] += fmaxf(maxO[rg][r] - TH_DIFF, 0.f);
                }
            }
    }
    #pragma unroll
    for (int m = 1; m < 64; m <<= 1) {
        #pragma unroll
        for (int j = 0; j < 4; ++j) s[j] += __shfl_xor(s[j], m);
    }

    __shared__ float wsum[4][4];
    if (lane == 0) {
        #pragma unroll
        for (int j = 0; j < 4; ++j) wsum[wave][j] = s[j];
    }
    __syncthreads();
    if (tid == 0) {
        float t[4] = {0.f, 0.f, 0.f, 0.f};
        for (int w = 0; w < 4; ++w)
            for (int j = 0; j < 4; ++j) t[j] += wsum[w][j];
        for (int j = 0; j < 4; ++j) partials[bid * 4 + j] = t[j];
    }
}

// ---------------------------------------------------------------- finalize
__global__ __launch_bounds__(256) void crloss_final(const float* __restrict__ partials,
                                                    const int* __restrict__ label,
                                                    float* __restrict__ out) {
    __shared__ int   cnt[kB][2];
    __shared__ float sums[kB][4];
    __shared__ float lossb[kB];
    const int tid = threadIdx.x;
    if (tid < kB * 2) (&cnt[0][0])[tid] = 0;
    __syncthreads();
    for (int idx = tid; idx < kB * kT; idx += 256) {
        const int l = label[idx];
        atomicAdd(&cnt[idx >> 11][l == 0 ? 0 : 1], 1);
    }
    // 256 partial entries, 16 consecutive per batch; shfl-reduce groups of 16
    float p[4];
    #pragma unroll
    for (int j = 0; j < 4; ++j) p[j] = partials[tid * 4 + j];
    #pragma unroll
    for (int m = 1; m <= 8; m <<= 1)
        #pragma unroll
        for (int j = 0; j < 4; ++j) p[j] += __shfl_xor(p[j], m);
    if ((tid & 15) == 0) {
        #pragma unroll
        for (int j = 0; j < 4; ++j) sums[tid >> 4][j] = p[j];
    }
    __syncthreads();
    if (tid < kB) {
        const int cf = cnt[tid][0], cr = cnt[tid][1];
        float l = 0.f;
        if (cf > 0 && cr > 0) {
            const float icf = 1.f / (float)cf, icr = 1.f / (float)cr;
            l = sums[tid][0] * icf + sums[tid][1] * icr +
                sums[tid][2] * icf + sums[tid][3] * icr;
        }
        lossb[tid] = l;
    }
    __syncthreads();
    if (tid == 0) {
        float tot = 0.f;
        for (int i = 0; i < kB; ++i) tot += lossb[i];
        out[0] = tot / (float)kB;
    }
}

// ---------------------------------------------------------------- launch
extern "C" void kernel_launch(void* const* d_in, const int* in_sizes, int n_in,
                              void* d_out, int out_size, void* d_ws, size_t ws_size,
                              hipStream_t stream) {
    const float* emb   = (const float*)d_in[0];
    const int*   label = (const int*)d_in[1];
    float*       out   = (float*)d_out;

    __hip_bfloat16* nrm = (__hip_bfloat16*)d_ws;                       // 8 MiB
    float* partials = (float*)((char*)d_ws + (size_t)kB * kT * kD * 2); // 4 KiB

    nrm_kernel<<<kB * kT / 4, 256, 0, stream>>>(emb, nrm);
    crloss_main<<<kB * (kT / RB), 256, 0, stream>>>(nrm, label, partials);
    crloss_final<<<1, 256, 0, stream>>>(partials, label, out);
}

// Round 2
// 50.862 us; speedup vs baseline: 2.1056x; 2.1056x over previous
//
#include <hip/hip_runtime.h>
#include <hip/hip_bf16.h>

typedef __bf16 bf16x8 __attribute__((ext_vector_type(8)));
typedef float  f32x4  __attribute__((ext_vector_type(4)));

namespace {
constexpr int kB = 16;
constexpr int kT = 2048;
constexpr int kD = 128;
constexpr int RB = 64;    // rows per block (4 waves x 16 rows)
constexpr int CT = 64;    // columns per LDS tile
constexpr float TH_SIM  = 0.9f;
constexpr float TH_DIFF = 0.1f;
constexpr float BIGF    = 1e9f;
}

// ---- async global->LDS, 16B per lane (dest = wave-uniform base + lane*16)
static __device__ __forceinline__ void gload_lds16(const short* g, short* l) {
    __builtin_amdgcn_global_load_lds(
        (const __attribute__((address_space(1))) void*)g,
        (__attribute__((address_space(3))) void*)l, 16, 0, 0);
}

// ---------------------------------------------------------------- label scan
// One block per batch: stable-partition positions (fakes first) + fake count.
__global__ __launch_bounds__(256) void scan_kernel(const int* __restrict__ label,
                                                   int* __restrict__ perm,
                                                   int* __restrict__ cFarr) {
    const int b = blockIdx.x, tid = threadIdx.x;
    const int* lb = label + b * kT;
    int loc[8], cnt = 0;
    #pragma unroll
    for (int j = 0; j < 8; ++j) { loc[j] = (lb[tid * 8 + j] == 0); cnt += loc[j]; }
    __shared__ int s[256];
    s[tid] = cnt;
    __syncthreads();
    for (int off = 1; off < 256; off <<= 1) {        // Hillis-Steele inclusive scan
        const int v = (tid >= off) ? s[tid - off] : 0;
        __syncthreads();
        s[tid] += v;
        __syncthreads();
    }
    const int total = s[255];
    if (tid == 0) cFarr[b] = total;
    int run = s[tid] - cnt;                          // exclusive prefix of fakes
    #pragma unroll
    for (int j = 0; j < 8; ++j) {
        const int i = tid * 8 + j;
        perm[b * kT + i] = loc[j] ? run : (total + i - run);
        run += loc[j];
    }
}

// ---------------------------------------------------------------- normalize + scatter
// One wave per row; write normalized bf16 row to its label-sorted position.
__global__ __launch_bounds__(256) void nrm_kernel(const float* __restrict__ emb,
                                                  const int* __restrict__ perm,
                                                  __hip_bfloat16* __restrict__ out) {
    const int wave = threadIdx.x >> 6;
    const int lane = threadIdx.x & 63;
    const int row  = blockIdx.x * 4 + wave;
    const float2 v = *reinterpret_cast<const float2*>(emb + (size_t)row * kD + lane * 2);
    float ss = v.x * v.x + v.y * v.y;
    #pragma unroll
    for (int m = 1; m < 64; m <<= 1) ss += __shfl_xor(ss, m);
    const float inv = ss > 0.f ? rsqrtf(ss) : 0.f;
    const int b   = row >> 11;
    const int dst = perm[row];
    __hip_bfloat162 o;
    o.x = __float2bfloat16(v.x * inv);
    o.y = __float2bfloat16(v.y * inv);
    *reinterpret_cast<__hip_bfloat162*>(out + ((size_t)(b * kT + dst)) * kD + lane * 2) = o;
}

// ---------------------------------------------------------------- main
// MODE 0: all cols fake; 1: all cols real; 2: mixed (boundary tile).
template <int MODE>
__device__ __forceinline__ void compute_tile(const short* __restrict__ buf,
                                             const bf16x8 (&afrag)[4],
                                             const float (&sgn)[4],
                                             float (&u1)[4], float (&u2)[4],
                                             int lo, int hi, int colBase, int cf) {
    #pragma unroll
    for (int g = 0; g < 4; ++g) {
        const int col = g * 16 + lo;
        bf16x8 bfrag[4];
        #pragma unroll
        for (int kk = 0; kk < 4; ++kk) {
            const int sh = (kk * 32 + hi * 8) ^ ((col & 7) << 3);
            bfrag[kk] = *reinterpret_cast<const bf16x8*>(&buf[col * kD + sh]);
        }
        f32x4 acc = {0.f, 0.f, 0.f, 0.f};
        #pragma unroll
        for (int kk = 0; kk < 4; ++kk)
            acc = __builtin_amdgcn_mfma_f32_16x16x32_bf16(afrag[kk], bfrag[kk], acc, 0, 0, 0);
        if (MODE == 0) {
            #pragma unroll
            for (int r = 0; r < 4; ++r) u1[r] = fminf(u1[r], acc[r] * sgn[r]);
        } else if (MODE == 1) {
            #pragma unroll
            for (int r = 0; r < 4; ++r) u2[r] = fminf(u2[r], -(acc[r] * sgn[r]));
        } else {
            const bool cfake = (colBase + col) < cf;
            #pragma unroll
            for (int r = 0; r < 4; ++r) {
                const float t = acc[r] * sgn[r];
                u1[r] = fminf(u1[r], cfake ? t : BIGF);
                u2[r] = fminf(u2[r], cfake ? BIGF : -t);
            }
        }
    }
}

__global__ __launch_bounds__(256, 2) void crloss_main(const __hip_bfloat16* __restrict__ nrm,
                                                      const int* __restrict__ cFarr,
                                                      float* __restrict__ partials) {
    __shared__ __align__(16) short lds[2][CT * kD];   // 2 x 16 KiB double buffer
    const int bid  = blockIdx.x;
    const int b    = bid >> 5;
    const int rb   = bid & 31;
    const int tid  = threadIdx.x;
    const int wave = tid >> 6;
    const int lane = tid & 63;
    const int lo   = lane & 15;
    const int hi   = lane >> 4;

    const short* nb = reinterpret_cast<const short*>(nrm) + (size_t)b * kT * kD;
    const int cf = cFarr[b];
    const int wave_row0 = rb * RB + wave * 16;

    // A fragments: lane holds row (lane&15), k = (lane>>4)*8 + e within 32-k block
    bf16x8 afrag[4];
    #pragma unroll
    for (int kk = 0; kk < 4; ++kk)
        afrag[kk] = *reinterpret_cast<const bf16x8*>(
            nb + (size_t)(wave_row0 + lo) * kD + kk * 32 + hi * 8);

    // per-acc-row sign: +1 if row fake (sorted rows < cf)
    float sgn[4];
    #pragma unroll
    for (int r = 0; r < 4; ++r)
        sgn[r] = (wave_row0 + hi * 4 + r < cf) ? 1.f : -1.f;

    float u1[4], u2[4];
    #pragma unroll
    for (int r = 0; r < 4; ++r) { u1[r] = BIGF; u2[r] = BIGF; }

    // staging: 1024 chunks of 16B; chunk c -> col=c>>4, pre-swizzled source, linear LDS
    auto stage = [&](int ct, int bufIdx) {
        #pragma unroll
        for (int p = 0; p < 4; ++p) {
            const int unit = p * 4 + wave;
            const int c    = unit * 64 + lane;
            const int col  = c >> 4;
            const int sh   = ((c & 15) * 8) ^ ((col & 7) << 3);   // short offset, pre-swizzled
            gload_lds16(nb + (size_t)(ct * CT + col) * kD + sh,
                        &lds[bufIdx][unit * 512]);
        }
    };

    const int  ctF    = cf >> 6;
    const bool hasMix = (cf & 63) != 0;

    stage(0, 0);
    __syncthreads();
    int cur = 0;
    for (int ct = 0; ct < kT / CT; ++ct) {
        if (ct + 1 < kT / CT) stage(ct + 1, cur ^ 1);   // prefetch overlaps compute
        if (ct < ctF)
            compute_tile<0>(lds[cur], afrag, sgn, u1, u2, lo, hi, ct * CT, cf);
        else if (ct == ctF && hasMix)
            compute_tile<2>(lds[cur], afrag, sgn, u1, u2, lo, hi, ct * CT, cf);
        else
            compute_tile<1>(lds[cur], afrag, sgn, u1, u2, lo, hi, ct * CT, cf);
        __syncthreads();   // drains prefetch (vmcnt 0) + guards buffer reuse
        cur ^= 1;
    }

    // merge the 16 col-lanes (same hi => same rows)
    #pragma unroll
    for (int m = 1; m <= 8; m <<= 1) {
        #pragma unroll
        for (int r = 0; r < 4; ++r) {
            u1[r] = fminf(u1[r], __shfl_xor(u1[r], m));
            u2[r] = fminf(u2[r], __shfl_xor(u2[r], m));
        }
    }

    // per-row losses; fake rows: minS=u1, maxO=-u2; real rows: minS=u2, maxO=-u1
    float sF = 0.f, sR = 0.f;
    if (lo == 0) {
        #pragma unroll
        for (int r = 0; r < 4; ++r) {
            const int  row = wave_row0 + hi * 4 + r;
            const bool f   = row < cf;
            const float mn = f ? u1[r] : u2[r];
            const float mx = f ? -u2[r] : -u1[r];
            const float l  = fmaxf(TH_SIM - mn, 0.f) + fmaxf(mx - TH_DIFF, 0.f);
            if (f) sF += l; else sR += l;
        }
    }
    #pragma unroll
    for (int m = 1; m < 64; m <<= 1) {
        sF += __shfl_xor(sF, m);
        sR += __shfl_xor(sR, m);
    }

    __shared__ float wsum[4][2];
    if (lane == 0) { wsum[wave][0] = sF; wsum[wave][1] = sR; }
    __syncthreads();
    if (tid == 0) {
        float a = 0.f, c = 0.f;
        for (int w = 0; w < 4; ++w) { a += wsum[w][0]; c += wsum[w][1]; }
        partials[bid * 2]     = a;
        partials[bid * 2 + 1] = c;
    }
}

// ---------------------------------------------------------------- finalize
__global__ __launch_bounds__(512) void crloss_final(const float* __restrict__ partials,
                                                    const int* __restrict__ cFarr,
                                                    float* __restrict__ out) {
    const int t = threadIdx.x;
    float pf = partials[t * 2];
    float pr = partials[t * 2 + 1];
    #pragma unroll
    for (int m = 1; m <= 16; m <<= 1) {   // reduce 32 consecutive entries (one batch)
        pf += __shfl_xor(pf, m);
        pr += __shfl_xor(pr, m);
    }
    __shared__ float sF[16], sR[16];
    if ((t & 31) == 0) { sF[t >> 5] = pf; sR[t >> 5] = pr; }
    __syncthreads();
    if (t == 0) {
        float tot = 0.f;
        for (int b = 0; b < kB; ++b) {
            const int cf = cFarr[b], cr = kT - cf;
            if (cf > 0 && cr > 0)
                tot += sF[b] / (float)cf + sR[b] / (float)cr;
        }
        out[0] = tot / (float)kB;
    }
}

// ---------------------------------------------------------------- launch
extern "C" void kernel_launch(void* const* d_in, const int* in_sizes, int n_in,
                              void* d_out, int out_size, void* d_ws, size_t ws_size,
                              hipStream_t stream) {
    const float* emb   = (const float*)d_in[0];
    const int*   label = (const int*)d_in[1];
    float*       out   = (float*)d_out;

    char* ws = (char*)d_ws;
    __hip_bfloat16* nrm = (__hip_bfloat16*)ws;                       // 8 MiB
    int*   perm     = (int*)(ws + (size_t)kB * kT * kD * 2);         // 128 KiB
    int*   cFarr    = (int*)(ws + (size_t)kB * kT * kD * 2 + kB * kT * 4);
    float* partials = (float*)(ws + (size_t)kB * kT * kD * 2 + kB * kT * 4 + 64);

    scan_kernel<<<kB, 256, 0, stream>>>(label, perm, cFarr);
    nrm_kernel<<<kB * kT / 4, 256, 0, stream>>>(emb, perm, nrm);
    crloss_main<<<kB * (kT / RB), 256, 0, stream>>>(nrm, cFarr, partials);
    crloss_final<<<1, 512, 0, stream>>>(partials, cFarr, out);
}